// Round 10
// baseline (217.425 us; speedup 1.0000x reference)
//
#include <hip/hip_runtime.h>
#include <hip/hip_bf16.h>

typedef __attribute__((ext_vector_type(8))) short short8;
typedef __attribute__((ext_vector_type(4))) short short4v;
typedef __attribute__((ext_vector_type(4))) float float4v;
typedef __attribute__((ext_vector_type(4))) unsigned uint4v;

#define SCALE2 0.06376540791556074f            // (1/sqrt(512)) * log2(e)
#define MBIAS2 -14426.950408889634f            // -10000 * log2(e)
#define EPST 136  // gemm epilogue LDS row stride (128 + 8)

__device__ inline unsigned short f2b(float f) {
    return __builtin_bit_cast(unsigned short, __float2bfloat16(f));
}
__device__ inline float b2f(unsigned short s) {
    return __uint_as_float(((unsigned)s) << 16);
}
__device__ inline unsigned pk2(float lo, float hi) {
    return (unsigned)f2b(lo) | ((unsigned)f2b(hi) << 16);
}
// async global->LDS, 16 bytes per lane; lds dest = wave-uniform base + lane*16
__device__ __forceinline__ void gld16(const unsigned short* g, unsigned short* l) {
    __builtin_amdgcn_global_load_lds(
        (const __attribute__((address_space(1))) void*)g,
        (__attribute__((address_space(3))) void*)l, 16, 0, 0);
}

// ------- prep: cast Q,K f32->bf16 (blocks 0..4095) + transpose weights (4096..5119)
__global__ void prep_kernel(const float* __restrict__ Q, const float* __restrict__ K,
                            const float* __restrict__ W0, const float* __restrict__ W1,
                            const float* __restrict__ W2, const float* __restrict__ W3,
                            unsigned short* __restrict__ Qb, unsigned short* __restrict__ Kb,
                            unsigned short* __restrict__ WT, int n) {
    __shared__ float tile[32][33];
    if (blockIdx.x < 4096) {
        int i = (blockIdx.x * 256 + threadIdx.x) * 8;
        const float* in;
        unsigned short* out;
        if (i < n) { in = Q + i; out = Qb + i; }
        else       { in = K + (i - n); out = Kb + (i - n); }
        float4v a = *(const float4v*)in;
        float4v b = *(const float4v*)(in + 4);
        uint4v o = {pk2(a[0], a[1]), pk2(a[2], a[3]), pk2(b[0], b[1]), pk2(b[2], b[3])};
        *(uint4v*)out = o;
    } else {
        int bid = blockIdx.x - 4096;
        int z = bid >> 8, rem = bid & 255;
        const float* W = (z == 0) ? W0 : (z == 1) ? W1 : (z == 2) ? W2 : W3;
        unsigned short* o = WT + (size_t)z * 512 * 512;
        int k0 = (rem >> 4) * 32, n0 = (rem & 15) * 32;
        int tx = threadIdx.x & 31, ty = threadIdx.x >> 5;
        for (int r = ty; r < 32; r += 8) tile[r][tx] = W[(size_t)(k0 + r) * 512 + n0 + tx];
        __syncthreads();
        for (int r = ty; r < 32; r += 8) o[(size_t)(n0 + r) * 512 + k0 + tx] = f2b(tile[tx][r]);
    }
}

// ---------------- bf16 MFMA GEMM, 8 waves, double-buffered 1-barrier --------
// (unchanged from round 9 for attribution)
__global__ __launch_bounds__(512) void gemm_kernel(
    const unsigned short* __restrict__ Qb, const unsigned short* __restrict__ Kb,
    const unsigned short* __restrict__ hb, const unsigned short* __restrict__ WT,
    const float* __restrict__ bq, const float* __restrict__ bk,
    const float* __restrict__ bv, const float* __restrict__ bo,
    unsigned short* __restrict__ qo, unsigned short* __restrict__ ko,
    unsigned short* __restrict__ vTo, unsigned short* __restrict__ to_,
    int zbase) {
    int z = zbase + blockIdx.z;
    const unsigned short* A = (z == 0) ? Qb : (z == 3) ? hb : Kb;
    const unsigned short* BT = WT + (size_t)z * 512 * 512;
    const float* bias = (z == 0) ? bq : (z == 1) ? bk : (z == 2) ? bv : bo;

    __shared__ unsigned short SM[4][8192];  // {A0,B0,A1,B1}, 64 KB

    int tid = threadIdx.x;
    int lane = tid & 63, wave = tid >> 6;
    int wr = wave >> 2, wc = wave & 3;
    int l15 = lane & 15, lg = lane >> 4, l7 = l15 & 7;
    int row0 = blockIdx.x * 128, col0 = blockIdx.y * 128;

    float4v acc[4][2];
#pragma unroll
    for (int m = 0; m < 4; m++)
#pragma unroll
        for (int n = 0; n < 2; n++) acc[m][n] = (float4v){0.f, 0.f, 0.f, 0.f};

    int sr8 = tid >> 3;
    int gch = (tid & 7) ^ (sr8 & 7);
    const unsigned short* gA0 = A + (size_t)(row0 + sr8) * 512 + gch * 8;
    const unsigned short* gB0 = BT + (size_t)(col0 + sr8) * 512 + gch * 8;

    auto STAGE = [&](int bi, int t) {
        int k0 = t * 64;
        unsigned short* lA = SM[bi * 2] + wave * 512;
        unsigned short* lB = SM[bi * 2 + 1] + wave * 512;
#pragma unroll
        for (int c = 0; c < 2; c++) {
            gld16(gA0 + (size_t)c * 32768 + k0, lA + c * 4096);
            gld16(gB0 + (size_t)c * 32768 + k0, lB + c * 4096);
        }
    };
    auto COMPUTE = [&](int bi) {
        const unsigned short* As = SM[bi * 2];
        const unsigned short* Bs = SM[bi * 2 + 1];
#pragma unroll
        for (int kk = 0; kk < 2; kk++) {
            int ck = ((kk * 4 + lg) ^ l7) * 8;
            short8 af[4], bf[2];
#pragma unroll
            for (int m = 0; m < 4; m++)
                af[m] = *(const short8*)(As + (wr * 64 + m * 16 + l15) * 64 + ck);
#pragma unroll
            for (int n = 0; n < 2; n++)
                bf[n] = *(const short8*)(Bs + (wc * 32 + n * 16 + l15) * 64 + ck);
#pragma unroll
            for (int m = 0; m < 4; m++)
#pragma unroll
                for (int n = 0; n < 2; n++)
                    acc[m][n] = __builtin_amdgcn_mfma_f32_16x16x32_bf16(af[m], bf[n], acc[m][n], 0, 0, 0);
        }
    };

    STAGE(0, 0);
    __syncthreads();
    int buf = 0;
    for (int t = 0; t < 7; t++) {
        STAGE(buf ^ 1, t + 1);
        COMPUTE(buf);
        __syncthreads();
        buf ^= 1;
    }
    COMPUTE(buf);

    if (z == 2) {
#pragma unroll
        for (int n = 0; n < 2; n++) {
            int col = col0 + wc * 32 + n * 16 + l15;
            float bias_v = bias[col];
            int h = col >> 6, d = col & 63;
#pragma unroll
            for (int m = 0; m < 4; m++) {
                int rowb = row0 + wr * 64 + m * 16 + lg * 4;
                int b = rowb >> 10, tq = rowb & 1023;
                float4v v = acc[m][n];
                short4v st;
#pragma unroll
                for (int r = 0; r < 4; r++) st[r] = (short)f2b(v[r] + bias_v);
                *(short4v*)(vTo + ((((size_t)b * 8 + h) * 64 + d) << 10) + tq) = st;
            }
        }
    } else {
        __syncthreads();
        unsigned short* ep = &SM[0][0];
#pragma unroll
        for (int n = 0; n < 2; n++) {
            int cl = wc * 32 + n * 16 + l15;
            float bias_v = bias[col0 + cl];
#pragma unroll
            for (int m = 0; m < 4; m++) {
                float4v v = acc[m][n];
#pragma unroll
                for (int r = 0; r < 4; r++) {
                    float x = v[r] + bias_v;
                    if (z == 3) x = x > 0.f ? x : 0.f;
                    ep[(wr * 64 + m * 16 + lg * 4 + r) * EPST + cl] = f2b(x);
                }
            }
        }
        __syncthreads();
        int rr = tid >> 4, cc = (tid & 15) * 8;
        unsigned short* o = (z == 0) ? qo : (z == 1) ? ko : to_;
#pragma unroll
        for (int p = 0; p < 4; p++) {
            int row_l = p * 32 + rr;
            short8 vv = *(const short8*)(ep + row_l * EPST + cc);
            size_t gidx = (size_t)(row0 + row_l) * 512 + col0 + cc;
            if (z == 3) {
                short8 hv = *(const short8*)(hb + gidx);
                short8 o8;
#pragma unroll
                for (int j = 0; j < 8; j++)
                    o8[j] = (short)f2b(b2f((unsigned short)vv[j]) + b2f((unsigned short)hv[j]));
                *(short8*)(o + gidx) = o8;
            } else {
                *(short8*)(o + gidx) = vv;
            }
        }
    }
}

// ---------------- flash attention + q-residual -------------------------------
// 8 waves (128 q-rows/block), grid (8,64) = 512 blocks, all co-resident.
// TRIPLE-buffered K/V, stage-ahead-2, ONE barrier/tile; within-wave pipeline:
// QK^T(t+1) [MFMA] issued alongside softmax(t) [VALU] -> PV(t).
// Safety: writer@t touches buf[(t+2)%3]; readers touch buf[t%3] (PV) and
// buf[(t+1)%3] (QK^T) -- disjoint; barrier separates t's reads from (t+1)'s write.
// K token t at row pi(t)=(t&0x23)|((t&4)<<2)|((t&0x18)>>1); chunk-XOR swizzle.
__global__ __launch_bounds__(512) void attn_kernel(
    const unsigned short* __restrict__ qb, const unsigned short* __restrict__ kb,
    const unsigned short* __restrict__ vT, const int* __restrict__ mask,
    unsigned short* __restrict__ ob) {
    __shared__ unsigned short Ks[3][64 * 64];
    __shared__ unsigned short Vs[3][64 * 64];
    __shared__ float mb[3][64];

    int tid = threadIdx.x;
    int lane = tid & 63, wave = tid >> 6;
    int l15 = lane & 15, lg = lane >> 4, l7 = l15 & 7;
    int bh = blockIdx.y;
    int b = bh >> 3, h = bh & 7;
    int qrow0 = b * 1024 + blockIdx.x * 128 + wave * 16;

    short8 qf[2];
#pragma unroll
    for (int kk = 0; kk < 2; kk++)
        qf[kk] = *(const short8*)(qb + (size_t)(qrow0 + l15) * 512 + h * 64 + kk * 32 + lg * 8);

    float l_acc = 0.f;
    float4v oacc[4];
#pragma unroll
    for (int n = 0; n < 4; n++) oacc[n] = (float4v){0.f, 0.f, 0.f, 0.f};

    // staging: 512 threads, 1 short8 per tensor per lane (64 rows x 8 chunks)
    int srow = tid >> 3, kch = tid & 7;
    int koff = kch * 8;
    int prow = (srow & 0x23) | ((srow & 4) << 2) | ((srow & 0x18) >> 1);
    int pkx = (kch ^ (prow & 7)) << 3, skx = (kch ^ (srow & 7)) << 3;

    short8 kreg, vreg;
    float mreg = 0.f;
    auto LOADR = [&](int t) {
        kreg = *(const short8*)(kb + (size_t)(b * 1024 + t * 64 + srow) * 512 + h * 64 + koff);
        vreg = *(const short8*)(vT + (((size_t)bh * 64 + srow) << 10) + t * 64 + koff);
        if (tid < 64) mreg = mask[b * 1024 + t * 64 + tid] ? 0.f : MBIAS2;
    };
    auto WLDS = [&](int bi) {
        *(short8*)(Ks[bi] + prow * 64 + pkx) = kreg;
        *(short8*)(Vs[bi] + srow * 64 + skx) = vreg;
        if (tid < 64) mb[bi][tid] = mreg;
    };
    auto QKT = [&](int bi, float (*S)[4]) {
        const unsigned short* Kc = Ks[bi];
#pragma unroll
        for (int jf = 0; jf < 4; jf++) {
            short8 kf0 = *(const short8*)(Kc + (jf * 16 + l15) * 64 + ((lg ^ l7) << 3));
            short8 kf1 = *(const short8*)(Kc + (jf * 16 + l15) * 64 + (((4 + lg) ^ l7) << 3));
            float4v tt = (float4v){0.f, 0.f, 0.f, 0.f};
            tt = __builtin_amdgcn_mfma_f32_16x16x32_bf16(kf0, qf[0], tt, 0, 0, 0);
            tt = __builtin_amdgcn_mfma_f32_16x16x32_bf16(kf1, qf[1], tt, 0, 0, 0);
#pragma unroll
            for (int r = 0; r < 4; r++) S[jf][r] = tt[r];
        }
    };

    // prologue: fill buffers 0,1; compute S(0); issue loads for tile 2
    LOADR(0); WLDS(0);
    LOADR(1); WLDS(1);
    __syncthreads();
    float S[4][4], Sn[4][4];
    QKT(0, S);
    LOADR(2);

#pragma unroll
    for (int t = 0; t < 16; t++) {
        int cur = t % 3, nxt = (t + 1) % 3, stg = (t + 2) % 3;

        // QK^T for t+1 issued first: MFMA latency hides under softmax VALU
        if (t < 15) QKT(nxt, Sn);

        // fixed-max exp2 softmax on S(t)
        float p[4][4];
#pragma unroll
        for (int jf = 0; jf < 4; jf++)
#pragma unroll
            for (int r = 0; r < 4; r++) {
                float e = exp2f(fmaf(S[jf][r], SCALE2,
                                     mb[cur][32 * (jf >> 1) + 8 * lg + 4 * (jf & 1) + r]));
                p[jf][r] = e;
                l_acc += e;
            }
        short8 pb[2];
#pragma unroll
        for (int ks = 0; ks < 2; ks++) {
            uint4v w = {pk2(p[2 * ks][0], p[2 * ks][1]), pk2(p[2 * ks][2], p[2 * ks][3]),
                        pk2(p[2 * ks + 1][0], p[2 * ks + 1][1]),
                        pk2(p[2 * ks + 1][2], p[2 * ks + 1][3])};
            pb[ks] = __builtin_bit_cast(short8, w);
        }
        // PV(t)
        const unsigned short* Vc = Vs[cur];
#pragma unroll
        for (int n = 0; n < 4; n++)
#pragma unroll
            for (int ks = 0; ks < 2; ks++) {
                short8 vf = *(const short8*)(Vc + (n * 16 + l15) * 64 + (((ks * 4 + lg) ^ l7) << 3));
                oacc[n] = __builtin_amdgcn_mfma_f32_16x16x32_bf16(vf, pb[ks], oacc[n], 0, 0, 0);
            }

        if (t < 14) WLDS(stg);          // stage tile t+2 (consumes LOADR(t+2))
        if (t < 13) LOADR(t + 3);       // issue loads for tile t+3
        if (t < 14) __syncthreads();

#pragma unroll
        for (int jf = 0; jf < 4; jf++)
#pragma unroll
            for (int r = 0; r < 4; r++) S[jf][r] = Sn[jf][r];   // elided by unroll
    }

    l_acc += __shfl_xor(l_acc, 16);
    l_acc += __shfl_xor(l_acc, 32);
    float inv = 1.f / l_acc;
#pragma unroll
    for (int n = 0; n < 4; n++) {
        size_t base = (size_t)(qrow0 + l15) * 512 + h * 64 + n * 16 + lg * 4;
        short4v qr = *(const short4v*)(qb + base);
        short4v st;
#pragma unroll
        for (int r = 0; r < 4; r++)
            st[r] = (short)f2b(b2f((unsigned short)qr[r]) + oacc[n][r] * inv);
        *(short4v*)(ob + base) = st;
    }
}

// ---------------- LayerNorm: 256 threads, 4 rows (1 wave each) ----------------
__global__ void ln_kernel_bf16(const unsigned short* __restrict__ in,
                               const float* __restrict__ g, const float* __restrict__ bb,
                               unsigned short* __restrict__ out) {
    int row = blockIdx.x * 4 + (threadIdx.x >> 6);
    int lane = threadIdx.x & 63;
    short8 v = *(const short8*)(in + (size_t)row * 512 + lane * 8);
    float x[8], s = 0.f, s2 = 0.f;
#pragma unroll
    for (int j = 0; j < 8; j++) {
        x[j] = b2f((unsigned short)v[j]);
        s += x[j];
        s2 += x[j] * x[j];
    }
#pragma unroll
    for (int off = 1; off < 64; off <<= 1) {
        s += __shfl_xor(s, off);
        s2 += __shfl_xor(s2, off);
    }
    float mu = s * (1.f / 512.f);
    float var = s2 * (1.f / 512.f) - mu * mu;
    float rs = rsqrtf(var + 1e-5f);
#pragma unroll
    for (int j = 0; j < 8; j++) {
        int c = lane * 8 + j;
        out[(size_t)row * 512 + c] = f2b((x[j] - mu) * rs * g[c] + bb[c]);
    }
}

__global__ void ln_kernel_f32(const unsigned short* __restrict__ in,
                              const float* __restrict__ g, const float* __restrict__ bb,
                              float* __restrict__ out) {
    int row = blockIdx.x * 4 + (threadIdx.x >> 6);
    int lane = threadIdx.x & 63;
    short8 v = *(const short8*)(in + (size_t)row * 512 + lane * 8);
    float x[8], s = 0.f, s2 = 0.f;
#pragma unroll
    for (int j = 0; j < 8; j++) {
        x[j] = b2f((unsigned short)v[j]);
        s += x[j];
        s2 += x[j] * x[j];
    }
#pragma unroll
    for (int off = 1; off < 64; off <<= 1) {
        s += __shfl_xor(s, off);
        s2 += __shfl_xor(s2, off);
    }
    float mu = s * (1.f / 512.f);
    float var = s2 * (1.f / 512.f) - mu * mu;
    float rs = rsqrtf(var + 1e-5f);
#pragma unroll
    for (int j = 0; j < 8; j++) {
        int c = lane * 8 + j;
        out[(size_t)row * 512 + c] = (x[j] - mu) * rs * g[c] + bb[c];
    }
}

extern "C" void kernel_launch(void* const* d_in, const int* in_sizes, int n_in,
                              void* d_out, int out_size, void* d_ws, size_t ws_size,
                              hipStream_t stream) {
    const float* Q = (const float*)d_in[0];
    const float* K = (const float*)d_in[1];
    const int* mask = (const int*)d_in[2];
    const float* Wq = (const float*)d_in[3];
    const float* bq = (const float*)d_in[4];
    const float* Wk = (const float*)d_in[5];
    const float* bk = (const float*)d_in[6];
    const float* Wv = (const float*)d_in[7];
    const float* bv = (const float*)d_in[8];
    const float* Wo = (const float*)d_in[9];
    const float* bo = (const float*)d_in[10];
    const float* g0 = (const float*)d_in[11];
    const float* b0 = (const float*)d_in[12];
    const float* g1 = (const float*)d_in[13];
    const float* b1 = (const float*)d_in[14];
    float* out = (float*)d_out;

    const size_t N = 8192ull * 512;
    unsigned short* w16 = (unsigned short*)d_ws;
    unsigned short* Qb = w16;
    unsigned short* Kb = Qb + N;
    unsigned short* WT = Kb + N;            // 4 x 512 x 512
    unsigned short* qb = WT + 4ull * 512 * 512;
    unsigned short* kb = qb + N;
    unsigned short* vTb = kb + N;
    unsigned short* obuf = vTb + N;
    unsigned short* hbuf = obuf + N;
    unsigned short* tbuf = hbuf + N;

    prep_kernel<<<5120, 256, 0, stream>>>(Q, K, Wq, Wk, Wv, Wo, Qb, Kb, WT, (int)N);
    gemm_kernel<<<dim3(64, 4, 3), 512, 0, stream>>>(Qb, Kb, hbuf, WT, bq, bk, bv, bo,
                                                    qb, kb, vTb, tbuf, 0);
    attn_kernel<<<dim3(8, 64), 512, 0, stream>>>(qb, kb, vTb, mask, obuf);
    ln_kernel_bf16<<<2048, 256, 0, stream>>>(obuf, g0, b0, hbuf);
    gemm_kernel<<<dim3(64, 4, 1), 512, 0, stream>>>(Qb, Kb, hbuf, WT, bq, bk, bv, bo,
                                                    qb, kb, vTb, tbuf, 3);
    ln_kernel_f32<<<2048, 256, 0, stream>>>(tbuf, g1, b1, out);
}